// Round 1
// baseline (422.819 us; speedup 1.0000x reference)
//
#include <hip/hip_runtime.h>

#define BLK 256

// ---------------- setup kernels ----------------

__global__ void k_deg(const int* __restrict__ dst, int* __restrict__ deg, int E) {
    int e = blockIdx.x * blockDim.x + threadIdx.x;
    if (e < E) atomicAdd(&deg[dst[e]], 1);
}

__global__ void k_dinv(const int* __restrict__ deg, float* __restrict__ dinv, int N) {
    int v = blockIdx.x * blockDim.x + threadIdx.x;
    if (v < N) {
        int d = deg[v];
        dinv[v] = (d > 0) ? (1.0f / sqrtf((float)d)) : 0.0f;
    }
}

// 3-kernel exclusive scan of deg[] -> row_off[] (and cursor[] copy)
__global__ void k_scan1(const int* __restrict__ deg, int* __restrict__ partials,
                        int N, int chunk) {
    __shared__ int sm[BLK];
    int b = blockIdx.x;
    int start = b * chunk;
    int end = min(start + chunk, N);
    int s = 0;
    for (int i = start + threadIdx.x; i < end; i += BLK) s += deg[i];
    sm[threadIdx.x] = s;
    __syncthreads();
    for (int off = BLK / 2; off > 0; off >>= 1) {
        if (threadIdx.x < off) sm[threadIdx.x] += sm[threadIdx.x + off];
        __syncthreads();
    }
    if (threadIdx.x == 0) partials[b] = sm[0];
}

__global__ void k_scan2(int* __restrict__ partials, int* __restrict__ row_off,
                        int N, int E) {
    __shared__ int sm[BLK];
    int t = threadIdx.x;
    sm[t] = partials[t];
    __syncthreads();
    for (int off = 1; off < BLK; off <<= 1) {
        int add = (t >= off) ? sm[t - off] : 0;
        __syncthreads();
        sm[t] += add;
        __syncthreads();
    }
    partials[t] = (t == 0) ? 0 : sm[t - 1];   // exclusive
    if (t == 0) row_off[N] = E;
}

__global__ void k_scan3(const int* __restrict__ deg, const int* __restrict__ partials,
                        int* __restrict__ row_off, int* __restrict__ cursor,
                        int N, int chunk) {
    __shared__ int sm[BLK];
    int b = blockIdx.x;
    int base = partials[b];
    int start = b * chunk;
    int end = min(start + chunk, N);
    for (int tile = start; tile < end; tile += BLK) {
        int idx = tile + threadIdx.x;
        int val = (idx < end) ? deg[idx] : 0;
        sm[threadIdx.x] = val;
        __syncthreads();
        for (int off = 1; off < BLK; off <<= 1) {
            int add = (threadIdx.x >= off) ? sm[threadIdx.x - off] : 0;
            __syncthreads();
            sm[threadIdx.x] += add;
            __syncthreads();
        }
        int excl = sm[threadIdx.x] - val;
        if (idx < end) {
            row_off[idx] = base + excl;
            cursor[idx]  = base + excl;
        }
        int tile_total = sm[BLK - 1];
        __syncthreads();
        base += tile_total;
    }
}

// pack one float4 per CSR slot: {src(bits), a_e, r_e, norm}
__global__ void k_fill(const int* __restrict__ src, const int* __restrict__ dst,
                       const float* __restrict__ attrs, const float* __restrict__ dinv,
                       int* __restrict__ cursor, float4* __restrict__ csr, int E) {
    int e = blockIdx.x * blockDim.x + threadIdx.x;
    if (e >= E) return;
    int s = src[e], t = dst[e];
    int pos = atomicAdd(&cursor[t], 1);
    float a = attrs[2 * e];
    float r = attrs[2 * e + 1];
    float nrm = dinv[s] * dinv[t];
    csr[pos] = make_float4(__int_as_float(s), a, r, nrm);
}

// ---------------- per-layer kernel: one wave per node, lane = dim ----------------
// x_new[v][d] = (sum_e norm_e * exp(s_ed) * x[src_e][d]) / (sum_e exp(s_ed) + eps)
// mode 0: out = emb + xn ; mode 1: out += xn ; mode 2: out = (out + xn) * 0.25
__global__ __launch_bounds__(BLK) void k_layer(
    const float* __restrict__ x, const float4* __restrict__ csr,
    const int* __restrict__ row_off,
    const float* __restrict__ aw, const float* __restrict__ rw,
    const float* __restrict__ emb, float* __restrict__ out,
    float* __restrict__ xout, int N, int mode) {
    int wave = threadIdx.x >> 6;
    int lane = threadIdx.x & 63;
    int v = blockIdx.x * 4 + wave;
    if (v >= N) return;
    float awd = aw[lane];
    float rwd = rw[lane];
    int s0 = row_off[v];
    int s1 = row_off[v + 1];
    float den = 0.0f, num = 0.0f;
    for (int i = s0; i < s1; ++i) {
        float4 ed = csr[i];
        int s = __float_as_int(ed.x);
        float sa = ed.y * awd; sa = (sa > 0.0f) ? sa : 0.01f * sa;
        float sr = ed.z * rwd; sr = (sr > 0.0f) ? sr : 0.01f * sr;
        float w = __expf(sa + sr);
        den += w;
        num += ed.w * w * x[(long)s * 64 + lane];
    }
    float xn = num / (den + 1e-16f);
    long o = (long)v * 64 + lane;
    if (xout) xout[o] = xn;
    if (mode == 0)      out[o] = emb[o] + xn;
    else if (mode == 1) out[o] += xn;
    else                out[o] = (out[o] + xn) * 0.25f;
}

// ---------------- launch ----------------

extern "C" void kernel_launch(void* const* d_in, const int* in_sizes, int n_in,
                              void* d_out, int out_size, void* d_ws, size_t ws_size,
                              hipStream_t stream) {
    const int*   ei    = (const int*)d_in[0];
    const float* attrs = (const float*)d_in[1];
    const float* emb   = (const float*)d_in[2];
    const float* a_att = (const float*)d_in[3];
    const float* r_att = (const float*)d_in[4];

    const int E = in_sizes[0] / 2;
    const int N = in_sizes[2] / 64;
    const int* src = ei;
    const int* dst = ei + E;

    char* ws = (char*)d_ws;
    size_t off = 0;
    auto alloc = [&](size_t bytes) {
        void* p = ws + off;
        off += (bytes + 255) & ~(size_t)255;
        return p;
    };
    int*    deg      = (int*)alloc((size_t)N * 4);
    float*  dinv     = (float*)alloc((size_t)N * 4);
    int*    row_off  = (int*)alloc((size_t)(N + 1) * 4);
    int*    cursor   = (int*)alloc((size_t)N * 4);
    int*    partials = (int*)alloc((size_t)BLK * 4);
    float4* csr      = (float4*)alloc((size_t)E * 16);
    float*  xA       = (float*)alloc((size_t)N * 64 * 4);
    float*  xB       = (float*)alloc((size_t)N * 64 * 4);
    float*  out      = (float*)d_out;

    hipMemsetAsync(deg, 0, (size_t)N * 4, stream);

    int gE = (E + BLK - 1) / BLK;
    int gN = (N + BLK - 1) / BLK;
    int chunk = (N + BLK - 1) / BLK;

    k_deg  <<<gE, BLK, 0, stream>>>(dst, deg, E);
    k_dinv <<<gN, BLK, 0, stream>>>(deg, dinv, N);
    k_scan1<<<BLK, BLK, 0, stream>>>(deg, partials, N, chunk);
    k_scan2<<<1,   BLK, 0, stream>>>(partials, row_off, N, E);
    k_scan3<<<BLK, BLK, 0, stream>>>(deg, partials, row_off, cursor, N, chunk);
    k_fill <<<gE, BLK, 0, stream>>>(src, dst, attrs, dinv, cursor, csr, E);

    int gL = (N + 3) / 4;  // one 64-lane wave per node, 4 waves/block
    k_layer<<<gL, BLK, 0, stream>>>(emb, csr, row_off, a_att,       r_att,       emb, out, xA,      N, 0);
    k_layer<<<gL, BLK, 0, stream>>>(xA,  csr, row_off, a_att + 64,  r_att + 64,  emb, out, xB,      N, 1);
    k_layer<<<gL, BLK, 0, stream>>>(xB,  csr, row_off, a_att + 128, r_att + 128, emb, out, nullptr, N, 2);
}

// Round 2
// 344.632 us; speedup vs baseline: 1.2269x; 1.2269x over previous
//
#include <hip/hip_runtime.h>

#define BLK 256
#define LBLK 1024   // layer kernel: 16 waves/block

// ---------------- setup kernels ----------------

__global__ void k_deg(const int* __restrict__ dst, int* __restrict__ deg, int E) {
    int e = blockIdx.x * blockDim.x + threadIdx.x;
    if (e < E) atomicAdd(&deg[dst[e]], 1);
}

// 3-kernel exclusive scan of deg[] -> row_off[] (and cursor[] copy)
__global__ void k_scan1(const int* __restrict__ deg, int* __restrict__ partials,
                        int N, int chunk) {
    __shared__ int sm[BLK];
    int b = blockIdx.x;
    int start = b * chunk;
    int end = min(start + chunk, N);
    int s = 0;
    for (int i = start + threadIdx.x; i < end; i += BLK) s += deg[i];
    sm[threadIdx.x] = s;
    __syncthreads();
    for (int off = BLK / 2; off > 0; off >>= 1) {
        if (threadIdx.x < off) sm[threadIdx.x] += sm[threadIdx.x + off];
        __syncthreads();
    }
    if (threadIdx.x == 0) partials[b] = sm[0];
}

__global__ void k_scan2(int* __restrict__ partials, int* __restrict__ row_off,
                        int N, int E) {
    __shared__ int sm[BLK];
    int t = threadIdx.x;
    sm[t] = partials[t];
    __syncthreads();
    for (int off = 1; off < BLK; off <<= 1) {
        int add = (t >= off) ? sm[t - off] : 0;
        __syncthreads();
        sm[t] += add;
        __syncthreads();
    }
    partials[t] = (t == 0) ? 0 : sm[t - 1];   // exclusive
    if (t == 0) row_off[N] = E;
}

__global__ void k_scan3(const int* __restrict__ deg, const int* __restrict__ partials,
                        int* __restrict__ row_off, int* __restrict__ cursor,
                        int N, int chunk) {
    __shared__ int sm[BLK];
    int b = blockIdx.x;
    int base = partials[b];
    int start = b * chunk;
    int end = min(start + chunk, N);
    for (int tile = start; tile < end; tile += BLK) {
        int idx = tile + threadIdx.x;
        int val = (idx < end) ? deg[idx] : 0;
        sm[threadIdx.x] = val;
        __syncthreads();
        for (int off = 1; off < BLK; off <<= 1) {
            int add = (threadIdx.x >= off) ? sm[threadIdx.x - off] : 0;
            __syncthreads();
            sm[threadIdx.x] += add;
            __syncthreads();
        }
        int excl = sm[threadIdx.x] - val;
        if (idx < end) {
            row_off[idx] = base + excl;
            cursor[idx]  = base + excl;
        }
        int tile_total = sm[BLK - 1];
        __syncthreads();
        base += tile_total;
    }
}

// pack one float4 per CSR slot: {src(bits), a_e, r_e, norm}; dinv folded in
__global__ void k_fill(const int* __restrict__ src, const int* __restrict__ dst,
                       const float* __restrict__ attrs, const int* __restrict__ deg,
                       int* __restrict__ cursor, float4* __restrict__ csr, int E) {
    int e = blockIdx.x * blockDim.x + threadIdx.x;
    if (e >= E) return;
    int s = src[e], t = dst[e];
    int pos = atomicAdd(&cursor[t], 1);
    float a = attrs[2 * e];
    float r = attrs[2 * e + 1];
    int ds = deg[s], dt = deg[t];               // dt >= 1 always (edge lands on t)
    float nrm = (ds > 0) ? (1.0f / sqrtf((float)ds * (float)dt)) : 0.0f;
    csr[pos] = make_float4(__int_as_float(s), a, r, nrm);
}

// ---------------- per-layer kernel ----------------
// one wave per node, lane = feature dim; 4-wide predicated edge unroll to
// pipeline the dependent csr->x[src] gather chain.
__device__ __forceinline__ float edge_w(float a, float r, float awd, float rwd) {
    float sa = a * awd; sa = (sa > 0.0f) ? sa : 0.01f * sa;
    float sr = r * rwd; sr = (sr > 0.0f) ? sr : 0.01f * sr;
    return __expf(sa + sr);
}

// MODE 0/1: xout[v] = xn  (layers 0,1)
// MODE 2:   out[v] = (emb[v] + xA[v] + xB[v] + xn) * 0.25  (layer 2)
template<int MODE>
__global__ __launch_bounds__(LBLK) void k_layer(
    const float* __restrict__ x, const float4* __restrict__ csr,
    const int* __restrict__ row_off,
    const float* __restrict__ aw, const float* __restrict__ rw,
    const float* __restrict__ emb, const float* __restrict__ xA,
    const float* __restrict__ xB,
    float* __restrict__ xout, float* __restrict__ out, int N) {
    const int lane = threadIdx.x & 63;
    const int wave = __builtin_amdgcn_readfirstlane(threadIdx.x >> 6);
    const int v = blockIdx.x * (LBLK / 64) + wave;      // wave-uniform (SGPR)
    if (v >= N) return;
    const float awd = aw[lane];
    const float rwd = rw[lane];
    const int s0 = row_off[v];
    const int s1 = row_off[v + 1];
    float den = 0.0f, num = 0.0f;
    for (int i = s0; i < s1; i += 4) {
        const int last = s1 - 1;
        // 4 independent edge records (clamped dup for short rows)
        float4 e0 = csr[i];
        float4 e1 = csr[min(i + 1, last)];
        float4 e2 = csr[min(i + 2, last)];
        float4 e3 = csr[min(i + 3, last)];
        // 4 independent gathers issue together
        float x0 = x[(size_t)(unsigned)__float_as_int(e0.x) * 64 + lane];
        float x1 = x[(size_t)(unsigned)__float_as_int(e1.x) * 64 + lane];
        float x2 = x[(size_t)(unsigned)__float_as_int(e2.x) * 64 + lane];
        float x3 = x[(size_t)(unsigned)__float_as_int(e3.x) * 64 + lane];
        float w0 = edge_w(e0.y, e0.z, awd, rwd);
        float w1 = (i + 1 < s1) ? edge_w(e1.y, e1.z, awd, rwd) : 0.0f;
        float w2 = (i + 2 < s1) ? edge_w(e2.y, e2.z, awd, rwd) : 0.0f;
        float w3 = (i + 3 < s1) ? edge_w(e3.y, e3.z, awd, rwd) : 0.0f;
        den += (w0 + w1) + (w2 + w3);
        num += (e0.w * w0 * x0 + e1.w * w1 * x1) + (e2.w * w2 * x2 + e3.w * w3 * x3);
    }
    const float xn = num / (den + 1e-16f);
    const size_t o = (size_t)v * 64 + lane;
    if (MODE == 2) out[o] = (emb[o] + xA[o] + xB[o] + xn) * 0.25f;
    else           xout[o] = xn;
}

// ---------------- launch ----------------

extern "C" void kernel_launch(void* const* d_in, const int* in_sizes, int n_in,
                              void* d_out, int out_size, void* d_ws, size_t ws_size,
                              hipStream_t stream) {
    const int*   ei    = (const int*)d_in[0];
    const float* attrs = (const float*)d_in[1];
    const float* emb   = (const float*)d_in[2];
    const float* a_att = (const float*)d_in[3];
    const float* r_att = (const float*)d_in[4];

    const int E = in_sizes[0] / 2;
    const int N = in_sizes[2] / 64;
    const int* src = ei;
    const int* dst = ei + E;

    char* ws = (char*)d_ws;
    size_t off = 0;
    auto alloc = [&](size_t bytes) {
        void* p = ws + off;
        off += (bytes + 255) & ~(size_t)255;
        return p;
    };
    int*    deg      = (int*)alloc((size_t)N * 4);
    int*    row_off  = (int*)alloc((size_t)(N + 1) * 4);
    int*    cursor   = (int*)alloc((size_t)N * 4);
    int*    partials = (int*)alloc((size_t)BLK * 4);
    float4* csr      = (float4*)alloc((size_t)E * 16);
    float*  xA       = (float*)alloc((size_t)N * 64 * 4);
    float*  xB       = (float*)alloc((size_t)N * 64 * 4);
    float*  out      = (float*)d_out;

    hipMemsetAsync(deg, 0, (size_t)N * 4, stream);

    int gE = (E + BLK - 1) / BLK;
    int chunk = (N + BLK - 1) / BLK;

    k_deg  <<<gE, BLK, 0, stream>>>(dst, deg, E);
    k_scan1<<<BLK, BLK, 0, stream>>>(deg, partials, N, chunk);
    k_scan2<<<1,   BLK, 0, stream>>>(partials, row_off, N, E);
    k_scan3<<<BLK, BLK, 0, stream>>>(deg, partials, row_off, cursor, N, chunk);
    k_fill <<<gE, BLK, 0, stream>>>(src, dst, attrs, deg, cursor, csr, E);

    int gL = (N + (LBLK / 64) - 1) / (LBLK / 64);   // one wave per node
    k_layer<0><<<gL, LBLK, 0, stream>>>(emb, csr, row_off, a_att,       r_att,
                                        nullptr, nullptr, nullptr, xA, nullptr, N);
    k_layer<1><<<gL, LBLK, 0, stream>>>(xA,  csr, row_off, a_att + 64,  r_att + 64,
                                        nullptr, nullptr, nullptr, xB, nullptr, N);
    k_layer<2><<<gL, LBLK, 0, stream>>>(xB,  csr, row_off, a_att + 128, r_att + 128,
                                        emb, xA, xB, nullptr, out, N);
}

// Round 3
// 295.441 us; speedup vs baseline: 1.4311x; 1.1665x over previous
//
#include <hip/hip_runtime.h>

#define BLK 256
#define LBLK 1024   // layer kernel: 16 waves/block, 4 nodes/wave, 64 nodes/block

// ---------------- setup kernels ----------------

__global__ void k_deg(const int* __restrict__ dst, int* __restrict__ deg, int E) {
    int e = blockIdx.x * blockDim.x + threadIdx.x;
    if (e < E) atomicAdd(&deg[dst[e]], 1);
}

// 3-kernel exclusive scan of deg[] -> row_off[] (and cursor[] copy)
__global__ void k_scan1(const int* __restrict__ deg, int* __restrict__ partials,
                        int N, int chunk) {
    __shared__ int sm[BLK];
    int b = blockIdx.x;
    int start = b * chunk;
    int end = min(start + chunk, N);
    int s = 0;
    for (int i = start + threadIdx.x; i < end; i += BLK) s += deg[i];
    sm[threadIdx.x] = s;
    __syncthreads();
    for (int off = BLK / 2; off > 0; off >>= 1) {
        if (threadIdx.x < off) sm[threadIdx.x] += sm[threadIdx.x + off];
        __syncthreads();
    }
    if (threadIdx.x == 0) partials[b] = sm[0];
}

__global__ void k_scan2(int* __restrict__ partials, int* __restrict__ row_off,
                        int N, int E) {
    __shared__ int sm[BLK];
    int t = threadIdx.x;
    sm[t] = partials[t];
    __syncthreads();
    for (int off = 1; off < BLK; off <<= 1) {
        int add = (t >= off) ? sm[t - off] : 0;
        __syncthreads();
        sm[t] += add;
        __syncthreads();
    }
    partials[t] = (t == 0) ? 0 : sm[t - 1];   // exclusive
    if (t == 0) row_off[N] = E;
}

__global__ void k_scan3(const int* __restrict__ deg, const int* __restrict__ partials,
                        int* __restrict__ row_off, int* __restrict__ cursor,
                        int N, int chunk) {
    __shared__ int sm[BLK];
    int b = blockIdx.x;
    int base = partials[b];
    int start = b * chunk;
    int end = min(start + chunk, N);
    for (int tile = start; tile < end; tile += BLK) {
        int idx = tile + threadIdx.x;
        int val = (idx < end) ? deg[idx] : 0;
        sm[threadIdx.x] = val;
        __syncthreads();
        for (int off = 1; off < BLK; off <<= 1) {
            int add = (threadIdx.x >= off) ? sm[threadIdx.x - off] : 0;
            __syncthreads();
            sm[threadIdx.x] += add;
            __syncthreads();
        }
        int excl = sm[threadIdx.x] - val;
        if (idx < end) {
            row_off[idx] = base + excl;
            cursor[idx]  = base + excl;
        }
        int tile_total = sm[BLK - 1];
        __syncthreads();
        base += tile_total;
    }
}

// pack one float4 per CSR slot: {src(bits), a_e, r_e, norm}; dinv folded in
__global__ void k_fill(const int* __restrict__ src, const int* __restrict__ dst,
                       const float* __restrict__ attrs, const int* __restrict__ deg,
                       int* __restrict__ cursor, float4* __restrict__ csr, int E) {
    int e = blockIdx.x * blockDim.x + threadIdx.x;
    if (e >= E) return;
    int s = src[e], t = dst[e];
    int pos = atomicAdd(&cursor[t], 1);
    float a = attrs[2 * e];
    float r = attrs[2 * e + 1];
    int ds = deg[s], dt = deg[t];               // dt >= 1 always (edge lands on t)
    float nrm = (ds > 0) ? (1.0f / sqrtf((float)ds * (float)dt)) : 0.0f;
    csr[pos] = make_float4(__int_as_float(s), a, r, nrm);
}

// ---------------- per-layer kernel ----------------
// lane = 16*sub + d4 : each wave handles 4 nodes (sub), each thread 4 dims
// (float4). Per-dim softmax -> w/den/num are float4, componentwise.

__device__ __forceinline__ float lrelu(float x) { return x > 0.0f ? x : 0.01f * x; }

__device__ __forceinline__ float4 edge_w4(float a, float r, const float4& aw, const float4& rw) {
    float4 w;
    w.x = __expf(lrelu(a * aw.x) + lrelu(r * rw.x));
    w.y = __expf(lrelu(a * aw.y) + lrelu(r * rw.y));
    w.z = __expf(lrelu(a * aw.z) + lrelu(r * rw.z));
    w.w = __expf(lrelu(a * aw.w) + lrelu(r * rw.w));
    return w;
}

__device__ __forceinline__ void acc4(float4& num, float4& den, float nrm,
                                     const float4& w, const float4& xv) {
    den.x += w.x; den.y += w.y; den.z += w.z; den.w += w.w;
    num.x += nrm * w.x * xv.x;
    num.y += nrm * w.y * xv.y;
    num.z += nrm * w.z * xv.z;
    num.w += nrm * w.w * xv.w;
}

// MODE 0/1: xout[v] = xn  (layers 0,1)
// MODE 2:   out[v] = (emb[v] + xA[v] + xB[v] + xn) * 0.25  (layer 2)
template<int MODE>
__global__ __launch_bounds__(LBLK) void k_layer(
    const float4* __restrict__ x4, const float4* __restrict__ csr,
    const int* __restrict__ row_off,
    const float4* __restrict__ aw4, const float4* __restrict__ rw4,
    const float4* __restrict__ emb4, const float4* __restrict__ xA4,
    const float4* __restrict__ xB4,
    float4* __restrict__ xout4, float4* __restrict__ out4, int N) {
    const int t = threadIdx.x;
    const int d4 = t & 15;            // which float4 of the 64-dim row
    const int nl = t >> 4;            // node index within block (0..63)
    const int v = blockIdx.x * (LBLK / 16) + nl;
    if (v >= N) return;
    const float4 aw = aw4[d4];
    const float4 rw = rw4[d4];
    const int s0 = row_off[v];
    const int s1 = row_off[v + 1];
    float4 num = {0.f, 0.f, 0.f, 0.f};
    float4 den = {0.f, 0.f, 0.f, 0.f};
    for (int i = s0; i < s1; i += 2) {
        const int last = s1 - 1;
        float4 e0 = csr[i];
        float4 e1 = csr[min(i + 1, last)];
        float4 x0 = x4[(size_t)(unsigned)__float_as_int(e0.x) * 16 + d4];
        float4 x1 = x4[(size_t)(unsigned)__float_as_int(e1.x) * 16 + d4];
        float4 w0 = edge_w4(e0.y, e0.z, aw, rw);
        float4 w1 = edge_w4(e1.y, e1.z, aw, rw);
        float g1 = (i + 1 < s1) ? 1.0f : 0.0f;   // kill the clamped dup
        w1.x *= g1; w1.y *= g1; w1.z *= g1; w1.w *= g1;
        acc4(num, den, e0.w, w0, x0);
        acc4(num, den, e1.w, w1, x1);
    }
    float4 xn;
    xn.x = num.x / (den.x + 1e-16f);
    xn.y = num.y / (den.y + 1e-16f);
    xn.z = num.z / (den.z + 1e-16f);
    xn.w = num.w / (den.w + 1e-16f);
    const size_t o = (size_t)v * 16 + d4;
    if (MODE == 2) {
        float4 e = emb4[o], A = xA4[o], B = xB4[o];
        float4 r;
        r.x = (e.x + A.x + B.x + xn.x) * 0.25f;
        r.y = (e.y + A.y + B.y + xn.y) * 0.25f;
        r.z = (e.z + A.z + B.z + xn.z) * 0.25f;
        r.w = (e.w + A.w + B.w + xn.w) * 0.25f;
        out4[o] = r;
    } else {
        xout4[o] = xn;
    }
}

// ---------------- launch ----------------

extern "C" void kernel_launch(void* const* d_in, const int* in_sizes, int n_in,
                              void* d_out, int out_size, void* d_ws, size_t ws_size,
                              hipStream_t stream) {
    const int*   ei    = (const int*)d_in[0];
    const float* attrs = (const float*)d_in[1];
    const float* emb   = (const float*)d_in[2];
    const float* a_att = (const float*)d_in[3];
    const float* r_att = (const float*)d_in[4];

    const int E = in_sizes[0] / 2;
    const int N = in_sizes[2] / 64;
    const int* src = ei;
    const int* dst = ei + E;

    char* ws = (char*)d_ws;
    size_t off = 0;
    auto alloc = [&](size_t bytes) {
        void* p = ws + off;
        off += (bytes + 255) & ~(size_t)255;
        return p;
    };
    int*    deg      = (int*)alloc((size_t)N * 4);
    int*    row_off  = (int*)alloc((size_t)(N + 1) * 4);
    int*    cursor   = (int*)alloc((size_t)N * 4);
    int*    partials = (int*)alloc((size_t)BLK * 4);
    float4* csr      = (float4*)alloc((size_t)E * 16);
    float4* xA       = (float4*)alloc((size_t)N * 64 * 4);
    float4* xB       = (float4*)alloc((size_t)N * 64 * 4);
    float4* out      = (float4*)d_out;

    hipMemsetAsync(deg, 0, (size_t)N * 4, stream);

    int gE = (E + BLK - 1) / BLK;
    int chunk = (N + BLK - 1) / BLK;

    k_deg  <<<gE, BLK, 0, stream>>>(dst, deg, E);
    k_scan1<<<BLK, BLK, 0, stream>>>(deg, partials, N, chunk);
    k_scan2<<<1,   BLK, 0, stream>>>(partials, row_off, N, E);
    k_scan3<<<BLK, BLK, 0, stream>>>(deg, partials, row_off, cursor, N, chunk);
    k_fill <<<gE, BLK, 0, stream>>>(src, dst, attrs, deg, cursor, csr, E);

    const float4* emb4 = (const float4*)emb;
    const float4* aw4  = (const float4*)a_att;
    const float4* rw4  = (const float4*)r_att;

    int gL = (N + (LBLK / 16) - 1) / (LBLK / 16);   // 64 nodes per block
    k_layer<0><<<gL, LBLK, 0, stream>>>(emb4, csr, row_off, aw4,      rw4,
                                        nullptr, nullptr, nullptr, xA, nullptr, N);
    k_layer<1><<<gL, LBLK, 0, stream>>>(xA,   csr, row_off, aw4 + 16, rw4 + 16,
                                        nullptr, nullptr, nullptr, xB, nullptr, N);
    k_layer<2><<<gL, LBLK, 0, stream>>>(xB,   csr, row_off, aw4 + 32, rw4 + 32,
                                        emb4, xA, xB, nullptr, out, N);
}

// Round 4
// 257.128 us; speedup vs baseline: 1.6444x; 1.1490x over previous
//
#include <hip/hip_runtime.h>

#define BLK 256
#define LBLK 256   // layer kernel: 4 waves/block, 16 threads per node, 16 nodes/block

// ---------------- bf16 helpers ----------------
__device__ __forceinline__ unsigned short f2bf(float f) {
    unsigned u = __float_as_uint(f);
    u += 0x7FFFu + ((u >> 16) & 1u);       // round-to-nearest-even
    return (unsigned short)(u >> 16);
}
__device__ __forceinline__ float bf2f(unsigned short h) {
    return __uint_as_float((unsigned)h << 16);
}
__device__ __forceinline__ float4 unpack4(ushort4 h) {
    return make_float4(bf2f(h.x), bf2f(h.y), bf2f(h.z), bf2f(h.w));
}
__device__ __forceinline__ ushort4 pack4(float4 f) {
    ushort4 h; h.x = f2bf(f.x); h.y = f2bf(f.y); h.z = f2bf(f.z); h.w = f2bf(f.w);
    return h;
}

// ---------------- setup kernels ----------------

// count degree by dst AND record each edge's rank within its dst row
__global__ void k_deg(const int* __restrict__ dst, int* __restrict__ deg,
                      int* __restrict__ rank, int E) {
    int e = blockIdx.x * blockDim.x + threadIdx.x;
    if (e < E) rank[e] = atomicAdd(&deg[dst[e]], 1);
}

__global__ void k_scan1(const int* __restrict__ deg, int* __restrict__ partials,
                        int N, int chunk) {
    __shared__ int sm[BLK];
    int b = blockIdx.x;
    int start = b * chunk;
    int end = min(start + chunk, N);
    int s = 0;
    for (int i = start + threadIdx.x; i < end; i += BLK) s += deg[i];
    sm[threadIdx.x] = s;
    __syncthreads();
    for (int off = BLK / 2; off > 0; off >>= 1) {
        if (threadIdx.x < off) sm[threadIdx.x] += sm[threadIdx.x + off];
        __syncthreads();
    }
    if (threadIdx.x == 0) partials[b] = sm[0];
}

// fused: every block redundantly scans the 256 partials for its base, then
// scans its own chunk of deg[] into row_off[]
__global__ void k_scan23(const int* __restrict__ deg, const int* __restrict__ partials,
                         int* __restrict__ row_off, int N, int E, int chunk) {
    __shared__ int sp[BLK];
    __shared__ int sm[BLK];
    int b = blockIdx.x;
    int t = threadIdx.x;
    sp[t] = partials[t];
    __syncthreads();
    for (int off = 1; off < BLK; off <<= 1) {
        int add = (t >= off) ? sp[t - off] : 0;
        __syncthreads();
        sp[t] += add;
        __syncthreads();
    }
    int base = (b == 0) ? 0 : sp[b - 1];
    if (b == 0 && t == 0) row_off[N] = E;
    __syncthreads();
    int start = b * chunk;
    int end = min(start + chunk, N);
    for (int tile = start; tile < end; tile += BLK) {
        int idx = tile + t;
        int val = (idx < end) ? deg[idx] : 0;
        sm[t] = val;
        __syncthreads();
        for (int off = 1; off < BLK; off <<= 1) {
            int add = (t >= off) ? sm[t - off] : 0;
            __syncthreads();
            sm[t] += add;
            __syncthreads();
        }
        if (idx < end) row_off[idx] = base + sm[t] - val;
        int tile_total = sm[BLK - 1];
        __syncthreads();
        base += tile_total;
    }
}

// embs[v] = bf16( dinv[v] * emb[v] )  — pre-scaled layer-0 input
__global__ void k_conv(const float4* __restrict__ emb4, const int* __restrict__ deg,
                       ushort4* __restrict__ embs, int N16) {
    int i = blockIdx.x * blockDim.x + threadIdx.x;
    if (i >= N16) return;
    int v = i >> 4;
    int d = deg[v];
    float dinv = (d > 0) ? rsqrtf((float)d) : 0.0f;
    float4 e = emb4[i];
    embs[i] = pack4(make_float4(dinv * e.x, dinv * e.y, dinv * e.z, dinv * e.w));
}

// atomic-free CSR fill: pos = row_off[dst] + rank; payload {src, a, r, pad}
__global__ void k_fill(const int* __restrict__ src, const int* __restrict__ dst,
                       const float* __restrict__ attrs, const int* __restrict__ row_off,
                       const int* __restrict__ rank, float4* __restrict__ csr, int E) {
    int e = blockIdx.x * blockDim.x + threadIdx.x;
    if (e >= E) return;
    int pos = row_off[dst[e]] + rank[e];
    float2 ar = ((const float2*)attrs)[e];
    csr[pos] = make_float4(__int_as_float(src[e]), ar.x, ar.y, 0.0f);
}

// ---------------- per-layer kernel ----------------
// 16 threads per node, each thread covers 4 dims (bf16x4 gather).
// xs rows are PRE-SCALED by dinv[src]:  x_new[v] = dinv[v] * (Σ w·xs[src]) / (Σ w + eps)
// MODE 0/1: xsout[v] = bf16( dinv[v] * x_new[v] )  (scaled for the next gather)
// MODE 2:   out[v] = (emb[v] + sqrt(deg)·xsA[v] + sqrt(deg)·xsB[v] + x_new) * 0.25

__device__ __forceinline__ float lrelu(float x) { return x > 0.0f ? x : 0.01f * x; }

__device__ __forceinline__ float4 edge_w4(float a, float r, const float4& aw, const float4& rw) {
    float4 w;
    w.x = __expf(lrelu(a * aw.x) + lrelu(r * rw.x));
    w.y = __expf(lrelu(a * aw.y) + lrelu(r * rw.y));
    w.z = __expf(lrelu(a * aw.z) + lrelu(r * rw.z));
    w.w = __expf(lrelu(a * aw.w) + lrelu(r * rw.w));
    return w;
}

template<int MODE>
__global__ __launch_bounds__(LBLK) void k_layer(
    const ushort4* __restrict__ xs, const float4* __restrict__ csr,
    const int* __restrict__ row_off, const int* __restrict__ deg,
    const float4* __restrict__ aw4, const float4* __restrict__ rw4,
    const float4* __restrict__ emb4,
    const ushort4* __restrict__ xsA, const ushort4* __restrict__ xsB,
    ushort4* __restrict__ xsout, float4* __restrict__ out4, int N) {
    const int t = threadIdx.x;
    const int d4 = t & 15;
    const int v = blockIdx.x * (LBLK / 16) + (t >> 4);
    if (v >= N) return;
    const float4 aw = aw4[d4];
    const float4 rw = rw4[d4];
    const int s0 = row_off[v];
    const int s1 = row_off[v + 1];
    const int dv = deg[v];
    float4 num = {0.f, 0.f, 0.f, 0.f};
    float4 den = {0.f, 0.f, 0.f, 0.f};
    for (int i = s0; i < s1; i += 2) {
        const int last = s1 - 1;
        float4 e0 = csr[i];
        float4 e1 = csr[min(i + 1, last)];
        ushort4 h0 = xs[(size_t)(unsigned)__float_as_int(e0.x) * 16 + d4];
        ushort4 h1 = xs[(size_t)(unsigned)__float_as_int(e1.x) * 16 + d4];
        float4 w0 = edge_w4(e0.y, e0.z, aw, rw);
        float4 w1 = edge_w4(e1.y, e1.z, aw, rw);
        float g1 = (i + 1 < s1) ? 1.0f : 0.0f;
        w1.x *= g1; w1.y *= g1; w1.z *= g1; w1.w *= g1;
        float4 x0 = unpack4(h0);
        float4 x1 = unpack4(h1);
        den.x += w0.x + w1.x; den.y += w0.y + w1.y;
        den.z += w0.z + w1.z; den.w += w0.w + w1.w;
        num.x += w0.x * x0.x + w1.x * x1.x;
        num.y += w0.y * x0.y + w1.y * x1.y;
        num.z += w0.z * x0.z + w1.z * x1.z;
        num.w += w0.w * x0.w + w1.w * x1.w;
    }
    float4 xr;   // raw ratio, before dinv[v] scaling
    xr.x = num.x / (den.x + 1e-16f);
    xr.y = num.y / (den.y + 1e-16f);
    xr.z = num.z / (den.z + 1e-16f);
    xr.w = num.w / (den.w + 1e-16f);
    const float dinv = (dv > 0) ? rsqrtf((float)dv) : 0.0f;
    const size_t o = (size_t)v * 16 + d4;
    if (MODE == 2) {
        const float sd = (dv > 0) ? sqrtf((float)dv) : 0.0f;
        float4 e = emb4[o];
        float4 A = unpack4(xsA[o]);
        float4 B = unpack4(xsB[o]);
        float4 r;
        r.x = (e.x + sd * (A.x + B.x) + dinv * xr.x) * 0.25f;
        r.y = (e.y + sd * (A.y + B.y) + dinv * xr.y) * 0.25f;
        r.z = (e.z + sd * (A.z + B.z) + dinv * xr.z) * 0.25f;
        r.w = (e.w + sd * (A.w + B.w) + dinv * xr.w) * 0.25f;
        out4[o] = r;
    } else {
        const float s = dinv * dinv;   // store dinv[v] * x_new = dinv^2 * xr
        xsout[o] = pack4(make_float4(s * xr.x, s * xr.y, s * xr.z, s * xr.w));
    }
}

// ---------------- launch ----------------

extern "C" void kernel_launch(void* const* d_in, const int* in_sizes, int n_in,
                              void* d_out, int out_size, void* d_ws, size_t ws_size,
                              hipStream_t stream) {
    const int*   ei    = (const int*)d_in[0];
    const float* attrs = (const float*)d_in[1];
    const float* emb   = (const float*)d_in[2];
    const float* a_att = (const float*)d_in[3];
    const float* r_att = (const float*)d_in[4];

    const int E = in_sizes[0] / 2;
    const int N = in_sizes[2] / 64;
    const int* src = ei;
    const int* dst = ei + E;

    char* ws = (char*)d_ws;
    size_t off = 0;
    auto alloc = [&](size_t bytes) {
        void* p = ws + off;
        off += (bytes + 255) & ~(size_t)255;
        return p;
    };
    int*     deg      = (int*)alloc((size_t)N * 4);
    int*     rank     = (int*)alloc((size_t)E * 4);
    int*     row_off  = (int*)alloc((size_t)(N + 1) * 4);
    int*     partials = (int*)alloc((size_t)BLK * 4);
    float4*  csr      = (float4*)alloc((size_t)E * 16);
    ushort4* embs     = (ushort4*)alloc((size_t)N * 16 * 8);
    ushort4* xsA      = (ushort4*)alloc((size_t)N * 16 * 8);
    ushort4* xsB      = (ushort4*)alloc((size_t)N * 16 * 8);
    float4*  out      = (float4*)d_out;

    hipMemsetAsync(deg, 0, (size_t)N * 4, stream);

    int gE = (E + BLK - 1) / BLK;
    int chunk = (N + BLK - 1) / BLK;

    k_deg   <<<gE, BLK, 0, stream>>>(dst, deg, rank, E);
    k_scan1 <<<BLK, BLK, 0, stream>>>(deg, partials, N, chunk);
    k_scan23<<<BLK, BLK, 0, stream>>>(deg, partials, row_off, N, E, chunk);
    k_conv  <<<(N * 16 + BLK - 1) / BLK, BLK, 0, stream>>>((const float4*)emb, deg, embs, N * 16);
    k_fill  <<<gE, BLK, 0, stream>>>(src, dst, attrs, row_off, rank, csr, E);

    const float4* emb4 = (const float4*)emb;
    const float4* aw4  = (const float4*)a_att;
    const float4* rw4  = (const float4*)r_att;

    int gL = (N + (LBLK / 16) - 1) / (LBLK / 16);
    k_layer<0><<<gL, LBLK, 0, stream>>>(embs, csr, row_off, deg, aw4,      rw4,
                                        nullptr, nullptr, nullptr, xsA, nullptr, N);
    k_layer<1><<<gL, LBLK, 0, stream>>>(xsA,  csr, row_off, deg, aw4 + 16, rw4 + 16,
                                        nullptr, nullptr, nullptr, xsB, nullptr, N);
    k_layer<2><<<gL, LBLK, 0, stream>>>(xsB,  csr, row_off, deg, aw4 + 32, rw4 + 32,
                                        emb4, xsA, xsB, nullptr, out, N);
}

// Round 5
// 242.239 us; speedup vs baseline: 1.7455x; 1.0615x over previous
//
#include <hip/hip_runtime.h>

#define BLK 256
#define LBLK 256   // layer kernel: 16 threads per node, 16 nodes/block
#define CH 1024    // scan chunk per block (N=200000 -> 196 blocks, <= 256)

// ---------------- bf16 helpers ----------------
__device__ __forceinline__ unsigned short f2bf(float f) {
    unsigned u = __float_as_uint(f);
    u += 0x7FFFu + ((u >> 16) & 1u);       // round-to-nearest-even
    return (unsigned short)(u >> 16);
}
__device__ __forceinline__ float bf2f(unsigned short h) {
    return __uint_as_float((unsigned)h << 16);
}
__device__ __forceinline__ float4 unpack4(ushort4 h) {
    return make_float4(bf2f(h.x), bf2f(h.y), bf2f(h.z), bf2f(h.w));
}
__device__ __forceinline__ ushort4 pack4(float4 f) {
    ushort4 h; h.x = f2bf(f.x); h.y = f2bf(f.y); h.z = f2bf(f.z); h.w = f2bf(f.w);
    return h;
}

// ---------------- setup kernels ----------------

// count degree by dst AND record each edge's rank within its dst row
__global__ void k_deg(const int* __restrict__ dst, int* __restrict__ deg,
                      int* __restrict__ rank, int E) {
    int e = blockIdx.x * blockDim.x + threadIdx.x;
    if (e < E) rank[e] = atomicAdd(&deg[dst[e]], 1);
}

// per-chunk sums (int4 loads, one reduce per block)
__global__ void k_scan1(const int* __restrict__ deg, int* __restrict__ partials, int N) {
    __shared__ int sm[BLK];
    int i0 = blockIdx.x * CH + threadIdx.x * 4;
    int s = 0;
    if (i0 + 3 < N) {
        int4 v = *(const int4*)(deg + i0);
        s = (v.x + v.y) + (v.z + v.w);
    } else {
        for (int k = 0; k < 4; ++k) if (i0 + k < N) s += deg[i0 + k];
    }
    sm[threadIdx.x] = s;
    __syncthreads();
    for (int off = BLK / 2; off > 0; off >>= 1) {
        if (threadIdx.x < off) sm[threadIdx.x] += sm[threadIdx.x + off];
        __syncthreads();
    }
    if (threadIdx.x == 0) partials[blockIdx.x] = sm[0];
}

// fused: redundant scan of partials for block base, then one vectorized
// LDS-scan tile over this block's 1024-element chunk -> row_off
__global__ void k_scan2(const int* __restrict__ deg, const int* __restrict__ partials,
                        int* __restrict__ row_off, int N, int E, int nb) {
    __shared__ int sp[BLK];
    __shared__ int sm[BLK];
    int b = blockIdx.x, t = threadIdx.x;
    sp[t] = (t < nb) ? partials[t] : 0;
    __syncthreads();
    for (int off = 1; off < BLK; off <<= 1) {
        int add = (t >= off) ? sp[t - off] : 0;
        __syncthreads();
        sp[t] += add;
        __syncthreads();
    }
    int base = (b == 0) ? 0 : sp[b - 1];
    if (b == 0 && t == 0) row_off[N] = E;
    int i0 = b * CH + t * 4;
    int v0 = 0, v1 = 0, v2 = 0, v3 = 0;
    if (i0 + 3 < N) {
        int4 v = *(const int4*)(deg + i0);
        v0 = v.x; v1 = v.y; v2 = v.z; v3 = v.w;
    } else {
        if (i0     < N) v0 = deg[i0];
        if (i0 + 1 < N) v1 = deg[i0 + 1];
        if (i0 + 2 < N) v2 = deg[i0 + 2];
    }
    int tot = (v0 + v1) + (v2 + v3);
    sm[t] = tot;
    __syncthreads();
    for (int off = 1; off < BLK; off <<= 1) {
        int add = (t >= off) ? sm[t - off] : 0;
        __syncthreads();
        sm[t] += add;
        __syncthreads();
    }
    int excl = base + sm[t] - tot;
    int4 r;
    r.x = excl;
    r.y = excl + v0;
    r.z = excl + v0 + v1;
    r.w = excl + v0 + v1 + v2;
    if (i0 + 3 < N) {
        *(int4*)(row_off + i0) = r;
    } else {
        if (i0     < N) row_off[i0]     = r.x;
        if (i0 + 1 < N) row_off[i0 + 1] = r.y;
        if (i0 + 2 < N) row_off[i0 + 2] = r.z;
    }
}

// fused conv + fill (independent jobs, one dispatch):
//  blocks [0,gF): atomic-free CSR fill, 8B records {src, bf16 a | bf16 r << 16}
//  blocks [gF,..): embs[v] = bf16(dinv[v] * emb[v])
__global__ void k_convfill(const int* __restrict__ src, const int* __restrict__ dst,
                           const float2* __restrict__ attrs, const int* __restrict__ row_off,
                           const int* __restrict__ rank, const int* __restrict__ deg,
                           uint2* __restrict__ csr, const float4* __restrict__ emb4,
                           ushort4* __restrict__ embs, int E, int N16, int gF) {
    int b = blockIdx.x;
    if (b < gF) {
        int e = b * BLK + threadIdx.x;
        if (e >= E) return;
        int pos = row_off[dst[e]] + rank[e];
        float2 ar = attrs[e];
        csr[pos] = make_uint2((unsigned)src[e],
                              (unsigned)f2bf(ar.x) | ((unsigned)f2bf(ar.y) << 16));
    } else {
        int i = (b - gF) * BLK + threadIdx.x;
        if (i >= N16) return;
        int d = deg[i >> 4];
        float dinv = (d > 0) ? rsqrtf((float)d) : 0.0f;
        float4 e = emb4[i];
        embs[i] = pack4(make_float4(dinv * e.x, dinv * e.y, dinv * e.z, dinv * e.w));
    }
}

// ---------------- per-layer kernel ----------------
// 16 threads per node, 4 dims each (bf16x4). xs rows PRE-SCALED by dinv[src].
// x_new[v] = dinv[v] * (Σ w·xs[src]) / (Σ w + eps)
// 4-edge unroll: deg<=4 rows (89%) finish in one gather round trip.

__device__ __forceinline__ float lrelu(float x) { return fmaxf(x, 0.01f * x); }

__device__ __forceinline__ float4 edge_w4(unsigned ar, const float4& aw, const float4& rw) {
    float a = bf2f((unsigned short)(ar & 0xffffu));
    float r = bf2f((unsigned short)(ar >> 16));
    float4 w;
    w.x = __expf(lrelu(a * aw.x) + lrelu(r * rw.x));
    w.y = __expf(lrelu(a * aw.y) + lrelu(r * rw.y));
    w.z = __expf(lrelu(a * aw.z) + lrelu(r * rw.z));
    w.w = __expf(lrelu(a * aw.w) + lrelu(r * rw.w));
    return w;
}

__device__ __forceinline__ void acc4(float4& num, float4& den,
                                     const float4& w, const ushort4& h, float g) {
    float4 x = unpack4(h);
    den.x += g * w.x; den.y += g * w.y; den.z += g * w.z; den.w += g * w.w;
    num.x += g * w.x * x.x;
    num.y += g * w.y * x.y;
    num.z += g * w.z * x.z;
    num.w += g * w.w * x.w;
}

template<int MODE>
__global__ __launch_bounds__(LBLK) void k_layer(
    const ushort4* __restrict__ xs, const uint2* __restrict__ csr,
    const int* __restrict__ row_off,
    const float4* __restrict__ aw4, const float4* __restrict__ rw4,
    const float4* __restrict__ emb4,
    const ushort4* __restrict__ xsA, const ushort4* __restrict__ xsB,
    ushort4* __restrict__ xsout, float4* __restrict__ out4, int N) {
    const int t = threadIdx.x;
    const int d4 = t & 15;
    const int v = blockIdx.x * (LBLK / 16) + (t >> 4);
    if (v >= N) return;
    const float4 aw = aw4[d4];
    const float4 rw = rw4[d4];
    const int s0 = row_off[v];
    const int s1 = row_off[v + 1];
    const int dv = s1 - s0;
    float4 num = {0.f, 0.f, 0.f, 0.f};
    float4 den = {0.f, 0.f, 0.f, 0.f};
    for (int i = s0; i < s1; i += 4) {
        const int last = s1 - 1;
        uint2 e0 = csr[i];
        uint2 e1 = csr[min(i + 1, last)];
        uint2 e2 = csr[min(i + 2, last)];
        uint2 e3 = csr[min(i + 3, last)];
        ushort4 h0 = xs[(size_t)e0.x * 16 + d4];
        ushort4 h1 = xs[(size_t)e1.x * 16 + d4];
        ushort4 h2 = xs[(size_t)e2.x * 16 + d4];
        ushort4 h3 = xs[(size_t)e3.x * 16 + d4];
        float4 w0 = edge_w4(e0.y, aw, rw);
        float4 w1 = edge_w4(e1.y, aw, rw);
        float4 w2 = edge_w4(e2.y, aw, rw);
        float4 w3 = edge_w4(e3.y, aw, rw);
        float g1 = (i + 1 < s1) ? 1.0f : 0.0f;
        float g2 = (i + 2 < s1) ? 1.0f : 0.0f;
        float g3 = (i + 3 < s1) ? 1.0f : 0.0f;
        acc4(num, den, w0, h0, 1.0f);
        acc4(num, den, w1, h1, g1);
        acc4(num, den, w2, h2, g2);
        acc4(num, den, w3, h3, g3);
    }
    float4 xr;   // raw ratio, before dinv[v] scaling
    xr.x = num.x / (den.x + 1e-16f);
    xr.y = num.y / (den.y + 1e-16f);
    xr.z = num.z / (den.z + 1e-16f);
    xr.w = num.w / (den.w + 1e-16f);
    const float dinv = (dv > 0) ? rsqrtf((float)dv) : 0.0f;
    const size_t o = (size_t)v * 16 + d4;
    if (MODE == 2) {
        const float sd = (dv > 0) ? sqrtf((float)dv) : 0.0f;
        float4 e = emb4[o];
        float4 A = unpack4(xsA[o]);
        float4 B = unpack4(xsB[o]);
        float4 r;
        r.x = (e.x + sd * (A.x + B.x) + dinv * xr.x) * 0.25f;
        r.y = (e.y + sd * (A.y + B.y) + dinv * xr.y) * 0.25f;
        r.z = (e.z + sd * (A.z + B.z) + dinv * xr.z) * 0.25f;
        r.w = (e.w + sd * (A.w + B.w) + dinv * xr.w) * 0.25f;
        out4[o] = r;
    } else {
        const float s = dinv * dinv;   // store dinv[v] * x_new = dinv^2 * xr
        xsout[o] = pack4(make_float4(s * xr.x, s * xr.y, s * xr.z, s * xr.w));
    }
}

// ---------------- launch ----------------

extern "C" void kernel_launch(void* const* d_in, const int* in_sizes, int n_in,
                              void* d_out, int out_size, void* d_ws, size_t ws_size,
                              hipStream_t stream) {
    const int*   ei    = (const int*)d_in[0];
    const float* attrs = (const float*)d_in[1];
    const float* emb   = (const float*)d_in[2];
    const float* a_att = (const float*)d_in[3];
    const float* r_att = (const float*)d_in[4];

    const int E = in_sizes[0] / 2;
    const int N = in_sizes[2] / 64;
    const int* src = ei;
    const int* dst = ei + E;

    char* ws = (char*)d_ws;
    size_t off = 0;
    auto alloc = [&](size_t bytes) {
        void* p = ws + off;
        off += (bytes + 255) & ~(size_t)255;
        return p;
    };
    int*     deg      = (int*)alloc((size_t)N * 4);
    int*     rank     = (int*)alloc((size_t)E * 4);
    int*     row_off  = (int*)alloc((size_t)(N + 1) * 4);
    int*     partials = (int*)alloc((size_t)BLK * 4);
    uint2*   csr      = (uint2*)alloc((size_t)E * 8);
    ushort4* embs     = (ushort4*)alloc((size_t)N * 16 * 8);
    ushort4* xsA      = (ushort4*)alloc((size_t)N * 16 * 8);
    ushort4* xsB      = (ushort4*)alloc((size_t)N * 16 * 8);
    float4*  out      = (float4*)d_out;

    hipMemsetAsync(deg, 0, (size_t)N * 4, stream);

    int gE = (E + BLK - 1) / BLK;
    int nb = (N + CH - 1) / CH;                 // 196 for N=200000 (must be <= 256)
    int gF = gE;
    int gC = (N * 16 + BLK - 1) / BLK;

    k_deg     <<<gE, BLK, 0, stream>>>(dst, deg, rank, E);
    k_scan1   <<<nb, BLK, 0, stream>>>(deg, partials, N);
    k_scan2   <<<nb, BLK, 0, stream>>>(deg, partials, row_off, N, E, nb);
    k_convfill<<<gF + gC, BLK, 0, stream>>>(src, dst, (const float2*)attrs, row_off,
                                            rank, deg, csr, (const float4*)emb,
                                            embs, E, N * 16, gF);

    const float4* emb4 = (const float4*)emb;
    const float4* aw4  = (const float4*)a_att;
    const float4* rw4  = (const float4*)r_att;

    int gL = (N + (LBLK / 16) - 1) / (LBLK / 16);
    k_layer<0><<<gL, LBLK, 0, stream>>>(embs, csr, row_off, aw4,      rw4,
                                        nullptr, nullptr, nullptr, xsA, nullptr, N);
    k_layer<1><<<gL, LBLK, 0, stream>>>(xsA,  csr, row_off, aw4 + 16, rw4 + 16,
                                        nullptr, nullptr, nullptr, xsB, nullptr, N);
    k_layer<2><<<gL, LBLK, 0, stream>>>(xsB,  csr, row_off, aw4 + 32, rw4 + 32,
                                        emb4, xsA, xsB, nullptr, out, N);
}